// Round 1
// baseline (1617.998 us; speedup 1.0000x reference)
//
#include <hip/hip_runtime.h>
#include <math.h>

// Problem constants (B=8, T=256 -> 2048 independent (b,t) pipelines)
#define NBT 2048

struct SM {
  alignas(16) float xp[240];      // zero-padded encoder input (nonzero in [80,160))
  alignas(16) float hsq[256];     // h^2 for top-64 ranking
  alignas(16) float hsel[256];    // masked hidden vector (decode input)
  float xres[80];
  float yres[80];
  float yal[80];
  float xele[80];
  float decsrc[80];
  float zb[80];
  float spad[238];                // padded buffer for sim windows
  float energy[84];               // 81 valid + 3 pad (tile of 28)
  float epart[112];               // 4 waves x 28
  float mp_self[256];
  float mp_src[256];
  float ext[160];
  float red[4];
  int   redi[4];
  unsigned char smask[80];
  int smask_t;
};

__device__ __forceinline__ float warpSum(float v){
  #pragma unroll
  for (int off = 32; off > 0; off >>= 1) v += __shfl_down(v, off, 64);
  return v;
}

__device__ __forceinline__ float blockSum(SM& sm, float v){
  v = warpSum(v);
  int wave = threadIdx.x >> 6;
  __syncthreads();                     // protect red[] from previous use
  if ((threadIdx.x & 63) == 0) sm.red[wave] = v;
  __syncthreads();
  return sm.red[0] + sm.red[1] + sm.red[2] + sm.red[3];
}

__device__ __forceinline__ float blockMax(SM& sm, float v){
  #pragma unroll
  for (int off = 32; off > 0; off >>= 1) v = fmaxf(v, __shfl_down(v, off, 64));
  __syncthreads();
  if ((threadIdx.x & 63) == 0) sm.red[threadIdx.x >> 6] = v;
  __syncthreads();
  return fmaxf(fmaxf(sm.red[0], sm.red[1]), fmaxf(sm.red[2], sm.red[3]));
}

// argmax with JAX tie rule: first (lowest index) max wins
__device__ __forceinline__ int blockArgMax(SM& sm, float v, int idx){
  #pragma unroll
  for (int off = 32; off > 0; off >>= 1){
    float ov = __shfl_down(v,  off, 64);
    int   oi = __shfl_down(idx, off, 64);
    if (ov > v || (ov == v && oi < idx)){ v = ov; idx = oi; }
  }
  __syncthreads();
  if ((threadIdx.x & 63) == 0){ sm.red[threadIdx.x >> 6] = v; sm.redi[threadIdx.x >> 6] = idx; }
  __syncthreads();
  float bv = sm.red[0]; int bi = sm.redi[0];
  #pragma unroll
  for (int w = 1; w < 4; w++){
    float wv = sm.red[w]; int wi = sm.redi[w];
    if (wv > bv || (wv == bv && wi < bi)){ bv = wv; bi = wi; }
  }
  return bi;   // every thread computes identical result
}

// top-64 membership via rank: rank = #{i: v_i > v_j} + #{i<j: v_i == v_j}; selected iff rank < 64.
// Exactly reproduces jax.lax.top_k one-hot mask semantics incl. stable ties.
__device__ __forceinline__ int rankTop64(SM& sm, float myv){
  int tid = threadIdx.x;
  int cnt = 0;
  const float4* q4 = (const float4*)sm.hsq;
  #pragma unroll 8
  for (int i4 = 0; i4 < 64; i4++){
    float4 o = q4[i4];
    int ib = i4 * 4;
    cnt += (o.x > myv || (o.x == myv && (ib + 0) < tid)) ? 1 : 0;
    cnt += (o.y > myv || (o.y == myv && (ib + 1) < tid)) ? 1 : 0;
    cnt += (o.z > myv || (o.z == myv && (ib + 2) < tid)) ? 1 : 0;
    cnt += (o.w > myv || (o.w == myv && (ib + 3) < tid)) ? 1 : 0;
  }
  return (cnt < 64) ? 1 : 0;
}

// sim_argmax: cosine sim over all 159 shifts of src vs yres; returns theta, fills yal = best window.
__device__ __forceinline__ int simArgmax(SM& sm, const float* src, float* yal_out){
  int tid = threadIdx.x;
  __syncthreads();
  if (tid < 238) sm.spad[tid] = (tid >= 79 && tid < 159) ? src[tid - 79] : 0.f;
  __syncthreads();
  float yv = (tid < 80) ? sm.yres[tid] : 0.f;
  float ny  = blockSum(sm, yv * yv);
  float nys = sqrtf(ny);
  float simv = -INFINITY;
  if (tid < 159){
    float num = 0.f, nx = 0.f;
    #pragma unroll 4
    for (int w = 0; w < 80; w++){
      float xa = sm.spad[tid + w];
      num += xa * sm.yres[w];
      nx  += xa * xa;
    }
    simv = num / (sqrtf(nx) * nys + 1e-6f);
  }
  int th = blockArgMax(sm, simv, tid);
  if (tid < 80) yal_out[tid] = sm.spad[th + tid];
  __syncthreads();
  return th;
}

// One branch: conv1d_encode (81 offsets, energy-argmax) + hsr + conv1d_decode + masked MSE loss.
// Thread j owns hidden column j. s-tiles of 28 (84 padded; s>=81 masked at argmax).
__device__ __forceinline__ void branchCompute(
    SM& sm, const float* __restrict__ We, float bej,
    const float* __restrict__ Wdec, const float* __restrict__ bdec,
    const float* enc_in, float* mask, const float* target,
    float* dec_out, int theta, bool first, float& lossAcc)
{
  int tid = threadIdx.x;
  __syncthreads();
  if (tid < 240) sm.xp[tid] = (tid >= 80 && tid < 160) ? enc_in[tid - 80] : 0.f;
  __syncthreads();

  const float* wep = We + tid;
  for (int t3 = 0; t3 < 3; t3++){
    int s0 = t3 * 28;
    // nonzero support: need w with 80 <= s0+k+w < 160 for some k in [0,28)
    int wlo = (s0 >= 53) ? 0 : ((80 - s0 - 27) & ~3);
    int whi = 160 - s0;                 // multiple of 4 for s0 in {0,28,56}
    float acc[28];
    #pragma unroll
    for (int k = 0; k < 28; k++) acc[k] = bej;
    for (int w = wlo; w < whi; w += 4){
      float wv0 = wep[(w + 0) * 256];
      float wv1 = wep[(w + 1) * 256];
      float wv2 = wep[(w + 2) * 256];
      float wv3 = wep[(w + 3) * 256];
      float xv[32];
      const float4* p4 = (const float4*)(sm.xp + s0 + w);   // 16B-aligned
      #pragma unroll
      for (int q = 0; q < 8; q++){
        float4 t = p4[q];
        xv[4*q] = t.x; xv[4*q+1] = t.y; xv[4*q+2] = t.z; xv[4*q+3] = t.w;
      }
      #pragma unroll
      for (int k = 0; k < 28; k++){
        acc[k] = fmaf(xv[k + 0], wv0, acc[k]);
        acc[k] = fmaf(xv[k + 1], wv1, acc[k]);
        acc[k] = fmaf(xv[k + 2], wv2, acc[k]);
        acc[k] = fmaf(xv[k + 3], wv3, acc[k]);
      }
    }
    int wave = tid >> 6, lane = tid & 63;
    #pragma unroll
    for (int k = 0; k < 28; k++){
      float v = warpSum(acc[k] * acc[k]);
      if (lane == 0) sm.epart[wave * 28 + k] = v;
    }
    __syncthreads();
    if (tid < 28)
      sm.energy[s0 + tid] = sm.epart[tid] + sm.epart[28 + tid] + sm.epart[56 + tid] + sm.epart[84 + tid];
    __syncthreads();
  }
  float ev = (tid < 81) ? sm.energy[tid] : -INFINITY;
  int ind = blockArgMax(sm, ev, tid);

  // recompute selected row h[ind, j]; nonzero support is exactly 80 terms
  float hv = bej;
  {
    int roff = 80 - ind;   // We row for w2=0
    #pragma unroll 4
    for (int w2 = 0; w2 < 80; w2++)
      hv = fmaf(sm.xp[80 + w2], wep[(w2 + roff) * 256], hv);
  }

  // hsr
  sm.hsq[tid] = hv * hv;
  __syncthreads();
  int sel1 = rankTop64(sm, hv * hv);
  float mpv = mask[tid];
  if (first){
    mask[tid] = (float)sel1;
    sm.hsel[tid] = sel1 ? hv : 0.f;
  } else {
    float interv = mpv * (float)sel1;
    if (interv > 0.f && !sm.smask_t){
      float dd = hv - (1.f - interv);
      lossAcc += dd * dd;
    }
    float h2 = (mpv > 0.f) ? 0.f : hv;
    __syncthreads();               // rank1 readers done before hsq rewrite
    sm.hsq[tid] = h2 * h2;
    __syncthreads();
    int sel2 = rankTop64(sm, h2 * h2);
    mask[tid] = mpv + (float)sel2;
    sm.hsel[tid] = sel2 ? h2 : 0.f;
  }
  __syncthreads();                 // hsel ready

  // decode: ext[d] = bdec[d] + sum_h hsel[h]*Wdec[h*160+d]
  if (tid < 160){
    float a = bdec[tid];
    const float4* h4 = (const float4*)sm.hsel;
    #pragma unroll 4
    for (int hi = 0; hi < 64; hi++){
      float4 hh = h4[hi];
      int hb = hi * 4;
      a = fmaf(hh.x, Wdec[(hb + 0) * 160 + tid], a);
      a = fmaf(hh.y, Wdec[(hb + 1) * 160 + tid], a);
      a = fmaf(hh.z, Wdec[(hb + 2) * 160 + tid], a);
      a = fmaf(hh.w, Wdec[(hb + 3) * 160 + tid], a);
    }
    sm.ext[tid] = a;
  }
  __syncthreads();

  float mv = fabsf((float)(theta - 79));
  bool gate = (mv > 40.0f);        // ETH
  if (tid < 80){
    float dec = sm.ext[ind + tid];
    dec_out[tid] = dec;            // residual update uses decoded output regardless of gates
    float diff = dec - target[tid];
    float l = (gate || sm.smask[tid]) ? 0.f : diff * diff;
    lossAcc += l / (mv + 1.0f);
  }
  __syncthreads();
}

__global__ void __launch_bounds__(64) zero_out_kernel(float* out){
  if (threadIdx.x == 0) out[0] = 0.f;
}

__global__ void __launch_bounds__(256) net_kernel(
    const float* __restrict__ x,  const float* __restrict__ y,
    const float* __restrict__ We, const float* __restrict__ be,
    const float* __restrict__ Wd, const float* __restrict__ bd,
    const float* __restrict__ Wds,const float* __restrict__ bds,
    float* out)
{
  __shared__ SM sm;
  int tid = threadIdx.x;
  int bt  = blockIdx.x;
  const float* xin = x + bt * 80;
  const float* yin = y + bt * 80;

  if (tid < 80){
    sm.xres[tid] = xin[tid];
    float yv = yin[tid];
    sm.yres[tid] = yv;
    sm.smask[tid] = (yv == 0.f) ? 1 : 0;   // seq_mask from ORIGINAL y
  }
  sm.mp_self[tid] = 0.f;
  sm.mp_src[tid]  = 0.f;
  __syncthreads();
  if (tid == 0){
    int a = 1;
    for (int i = 0; i < 80; i++) a &= (int)sm.smask[i];
    sm.smask_t = a;
  }
  __syncthreads();

  float bej = be[tid];
  float lossAcc = 0.f;

  for (int it = 0; it < 4; it++){
    bool first = (it == 0);

    // --- align x_res to y_res ---
    int th1 = simArgmax(sm, sm.xres, sm.yal);

    // --- attention softmax(y_al * y_res) and z = y_al * attn ---
    float pv = (tid < 80) ? sm.yal[tid] * sm.yres[tid] : -INFINITY;
    float mx = blockMax(sm, pv);
    float e  = (tid < 80) ? expf(pv - mx) : 0.f;
    float ssum = blockSum(sm, e);
    if (tid < 80) sm.zb[tid] = sm.yal[tid] * (e / ssum);
    __syncthreads();

    // --- reverse shift: x_ele[d] = z[d + 79 - theta] ---
    if (tid < 80){
      int q = tid + 79 - th1;
      sm.xele[tid] = (q >= 0 && q < 80) ? sm.zb[q] : 0.f;
    }

    // --- self branch: encode/hsr/decode x_ele, loss vs x_res, dec -> xele ---
    branchCompute(sm, We, bej, Wds, bds, sm.xele, sm.mp_self, sm.xres, sm.xele, th1, first, lossAcc);

    // --- re-align decoded x_ele to y_res ---
    int th2 = simArgmax(sm, sm.xele, sm.yal);

    // --- src branch: encode/hsr/decode y_al, loss vs y_res, dec -> decsrc ---
    branchCompute(sm, We, bej, Wd, bd, sm.yal, sm.mp_src, sm.yres, sm.decsrc, th2, first, lossAcc);

    // --- residual updates ---
    __syncthreads();
    if (tid < 80){
      sm.xres[tid] -= sm.xele[tid];
      sm.yres[tid] -= sm.decsrc[tid];
    }
    __syncthreads();
  }

  float total = blockSum(sm, lossAcc);
  if (tid == 0) atomicAdd(out, total * 0.25f);   // mean over 4 iterations
}

extern "C" void kernel_launch(void* const* d_in, const int* in_sizes, int n_in,
                              void* d_out, int out_size, void* d_ws, size_t ws_size,
                              hipStream_t stream) {
  const float* x   = (const float*)d_in[0];
  const float* y   = (const float*)d_in[1];
  const float* We  = (const float*)d_in[2];
  const float* be  = (const float*)d_in[3];
  const float* Wd  = (const float*)d_in[4];
  const float* bd  = (const float*)d_in[5];
  const float* Wds = (const float*)d_in[6];
  const float* bds = (const float*)d_in[7];
  float* out = (float*)d_out;

  hipLaunchKernelGGL(zero_out_kernel, dim3(1), dim3(64), 0, stream, out);
  hipLaunchKernelGGL(net_kernel, dim3(NBT), dim3(256), 0, stream,
                     x, y, We, be, Wd, bd, Wds, bds, out);
}